// Round 4
// baseline (545.760 us; speedup 1.0000x reference)
//
#include <hip/hip_runtime.h>

typedef __bf16 bf8 __attribute__((ext_vector_type(8)));
typedef float f4 __attribute__((ext_vector_type(4)));
typedef unsigned short us4 __attribute__((ext_vector_type(4)));

#define MFMA16(a,b,c) __builtin_amdgcn_mfma_f32_16x16x32_bf16((a),(b),(c),0,0,0)

__device__ __forceinline__ unsigned short f2bfu(float f){
  __bf16 h = (__bf16)f;
  union { __bf16 b; unsigned short u; } v; v.b = h; return v.u;
}

// Wave-local LDS fence: stalls THIS wave until its DS ops completed; compiler
// memory clobber stops reordering. Does NOT drain vmcnt -> global prefetch
// loads stay in flight across layers. Act buffers are wave-private, so this
// replaces __syncthreads() between MLP layers.
__device__ __forceinline__ void wfence(){
  asm volatile("s_waitcnt lgkmcnt(0)" ::: "memory");
}

// LDS layout (ushort element offsets)
#define OFF_W1   0       // 32->64 : 1 kstep * 4 mtiles * 512 = 2048
#define OFF_W2   2048    // 64->64 : 2*4*512 = 4096
#define OFF_W3   6144    // 64->16 : 2*1*512 = 1024
#define OFF_CW1  7168    // 16->64 : 1*4*512 = 2048 (zero-padded K)
#define OFF_CW2  9216    // 64->64 : 4096
#define OFF_CW3  13312   // 64->64 : 4096
#define OFF_CW4  17408   // 64->3  : 2*1*512 = 1024 (zero-padded M)
#define OFF_ACT  18432
#define ACT_STRIDE 72    // 64 features + 8 pad
#define SMEM_US  (18432 + 4*16*ACT_STRIDE)

// bias offsets (floats)
#define BO_B1  0
#define BO_B2  64
#define BO_B3  128
#define BO_CB1 144
#define BO_CB2 208
#define BO_CB3 272
#define BO_CB4 336

// Stage weights from global (fin x fout row-major FP32) into LDS as bf16 in
// A-fragment order.
template<int FIN,int FOUT,int KS,int MT>
__device__ __forceinline__ void stage_w(const float* w, unsigned short* dst){
  const int total = KS*MT*512;
  for (int e = threadIdx.x; e < total; e += 256){
    int chunk = e >> 9;
    int s = chunk / MT, t = chunk % MT;
    int le = e & 511;
    int lane = le >> 3, j = le & 7;
    int q = lane >> 4, m = lane & 15;
    int i = s*32 + q*8 + j;
    int o = t*16 + m;
    dst[e] = (i < FIN && o < FOUT) ? f2bfu(w[i*FOUT + o]) : (unsigned short)0;
  }
}

// Per-lane gather state for one iteration (4 levels x 8 corners), kept in VGPRs
// so the global loads overlap the previous iteration's MLP.
struct GBuf {
  float2 cv[4][8];
  float wx[4], wy[4], wz[4];
};

__device__ __forceinline__ void hash_gather(const float* __restrict__ xin,
    const float2* __restrict__ tabq, const int* res_, int q, int gpl, GBuf& g){
  const float px = xin[gpl*3+0];
  const float py = xin[gpl*3+1];
  const float pz = xin[gpl*3+2];
#pragma unroll
  for (int d = 0; d < 4; ++d){
    const int res = res_[d];
    const float sc = 0.5f*(float)(res-1);
    const float xs=(px+1.f)*sc, ys=(py+1.f)*sc, zs=(pz+1.f)*sc;
    const float fx=floorf(xs), fy=floorf(ys), fz=floorf(zs);
    g.wx[d]=xs-fx; g.wy[d]=ys-fy; g.wz[d]=zs-fz;
    int ix0=min(max((int)fx,0),res-1);
    int iy0=min(max((int)fy,0),res-1);
    int iz0=min(max((int)fz,0),res-1);
    int ix1=min(ix0+1,res-1), iy1=min(iy0+1,res-1), iz1=min(iz0+1,res-1);
    const bool dense = (q==0) && (d<3);   // levels 0..2: 16^3,20^3,25^3 <= 16384
    unsigned X0,X1,Y0,Y1,Z0,Z1;
    if (dense){
      X0=(unsigned)ix0;            X1=(unsigned)ix1;
      Y0=(unsigned)(res*iy0);      Y1=(unsigned)(res*iy1);
      Z0=(unsigned)(res*res*iz0);  Z1=(unsigned)(res*res*iz1);
    } else {
      X0=(unsigned)ix0;                 X1=(unsigned)ix1;
      Y0=(unsigned)iy0*2654435761u;     Y1=(unsigned)iy1*2654435761u;
      Z0=(unsigned)iz0*805459861u;      Z1=(unsigned)iz1*805459861u;
    }
    const float2* tl = tabq + (d<<14);
#pragma unroll
    for (int c = 0; c < 8; ++c){
      unsigned xc = (c&1)?X1:X0;
      unsigned yc = (c&2)?Y1:Y0;
      unsigned zc = (c&4)?Z1:Z0;
      unsigned idx = dense ? (xc+yc+zc) : ((xc^yc^zc)&16383u);
      g.cv[d][c] = tl[idx];
    }
  }
}

__device__ __forceinline__ bf8 hash_combine(const GBuf& g){
  bf8 b;
#pragma unroll
  for (int d = 0; d < 4; ++d){
    const float wx=g.wx[d], wy=g.wy[d], wz=g.wz[d];
    const float wx0=1.f-wx, wy0=1.f-wy, wz0=1.f-wz;
    float f0=0.f, f1=0.f;
#pragma unroll
    for (int c = 0; c < 8; ++c){
      float wc = ((c&1)?wx:wx0) * ((c&2)?wy:wy0) * ((c&4)?wz:wz0);
      f0 += wc*g.cv[d][c].x;
      f1 += wc*g.cv[d][c].y;
    }
    b[2*d]   = (__bf16)f0;
    b[2*d+1] = (__bf16)f1;
  }
  return b;
}

// One 64->64 layer for one wave's 16-point tile, LDS act round-trip.
__device__ __forceinline__ void layer64(const unsigned short* wlds, const float* bias,
                                        unsigned short* act, int lane, bool relu){
  const int q = lane >> 4, m = lane & 15;
  bf8 b0 = *(const bf8*)(act + m*ACT_STRIDE + q*8);        // k = 0..31
  bf8 b1 = *(const bf8*)(act + m*ACT_STRIDE + 32 + q*8);   // k = 32..63
  f4 acc[4];
#pragma unroll
  for (int t = 0; t < 4; ++t){
    f4 c = {0.f,0.f,0.f,0.f};
    c = MFMA16(*(const bf8*)(wlds + ((0*4+t)*64+lane)*8), b0, c);
    c = MFMA16(*(const bf8*)(wlds + ((1*4+t)*64+lane)*8), b1, c);
    acc[t] = c;
  }
#pragma unroll
  for (int t = 0; t < 4; ++t){
    us4 pk;
#pragma unroll
    for (int r = 0; r < 4; ++r){
      float v = acc[t][r] + bias[t*16 + q*4 + r];
      if (relu) v = fmaxf(v, 0.f);
      pk[r] = f2bfu(v);
    }
    *(us4*)(act + m*ACT_STRIDE + t*16 + q*4) = pk;
  }
}

__global__ __launch_bounds__(256,3) void nerf_fused(
    const float* __restrict__ xin, const float* __restrict__ tab,
    const float* __restrict__ w1,  const float* __restrict__ b1,
    const float* __restrict__ w2,  const float* __restrict__ b2,
    const float* __restrict__ w3,  const float* __restrict__ b3,
    const float* __restrict__ cw1, const float* __restrict__ cb1,
    const float* __restrict__ cw2, const float* __restrict__ cb2,
    const float* __restrict__ cw3, const float* __restrict__ cb3,
    const float* __restrict__ cw4, const float* __restrict__ cb4,
    float* __restrict__ out, int nB)
{
  __shared__ __align__(16) unsigned short smem[SMEM_US];
  __shared__ __align__(16) float sbias[340];
  __shared__ int sres[16];

  stage_w<32,64,1,4>(w1,  smem+OFF_W1);
  stage_w<64,64,2,4>(w2,  smem+OFF_W2);
  stage_w<64,16,2,1>(w3,  smem+OFF_W3);
  stage_w<16,64,1,4>(cw1, smem+OFF_CW1);
  stage_w<64,64,2,4>(cw2, smem+OFF_CW2);
  stage_w<64,64,2,4>(cw3, smem+OFF_CW3);
  stage_w<64, 3,2,1>(cw4, smem+OFF_CW4);
  {
    int t = threadIdx.x;
    if (t < 64){
      sbias[BO_B1 +t] = b1[t];
      sbias[BO_B2 +t] = b2[t];
      sbias[BO_CB1+t] = cb1[t];
      sbias[BO_CB2+t] = cb2[t];
      sbias[BO_CB3+t] = cb3[t];
    }
    if (t < 16) sbias[BO_B3+t] = b3[t];
    if (t < 3)  sbias[BO_CB4+t] = cb4[t];
    if (t < 16){
      const int RES_[16] = {16,20,25,32,40,50,64,80,101,128,161,203,256,322,406,512};
      sres[t] = RES_[t];
    }
  }
  __syncthreads();   // weights/bias staging -> everything (only block barrier)

  const int lane = threadIdx.x & 63, wv = threadIdx.x >> 6;
  const int q = lane >> 4, m = lane & 15;
  unsigned short* act = smem + OFF_ACT + wv*16*ACT_STRIDE;
  const float2* tabq = (const float2*)tab + ((4*q)<<14);   // this lane's level group

  int res_[4];
#pragma unroll
  for (int d = 0; d < 4; ++d) res_[d] = sres[4*q + d];

  const int base = blockIdx.x*256 + wv*64 + m;

  GBuf g;
  hash_gather(xin, tabq, res_, q, min(base, nB-1), g);

#pragma unroll
  for (int it = 0; it < 4; ++it){
    const int gp = base + it*16;

    // prefetch next iteration's table corners; loads stay in flight across the
    // MLP below (fences are lgkmcnt-only).
    GBuf gn;
    if (it < 3) hash_gather(xin, tabq, res_, q, min(base + (it+1)*16, nB-1), gn);

    // ---- trilinear combine: this lane's 8 features ARE its L1 B-fragment ----
    bf8 bfrag = hash_combine(g);

    // ---- L1: 32->64, relu ----
    {
      f4 acc[4];
#pragma unroll
      for (int t = 0; t < 4; ++t){
        f4 c = {0.f,0.f,0.f,0.f};
        acc[t] = MFMA16(*(const bf8*)(smem + OFF_W1 + (t*64+lane)*8), bfrag, c);
      }
#pragma unroll
      for (int t = 0; t < 4; ++t){
        us4 pk;
#pragma unroll
        for (int r = 0; r < 4; ++r){
          float v = fmaxf(acc[t][r] + sbias[BO_B1 + t*16 + q*4 + r], 0.f);
          pk[r] = f2bfu(v);
        }
        *(us4*)(act + m*ACT_STRIDE + t*16 + q*4) = pk;
      }
    }
    wfence();   // L1 act write -> L2 read (wave-local)

    // ---- L2: 64->64 relu ----
    layer64(smem+OFF_W2, sbias+BO_B2, act, lane, true);
    wfence();

    // ---- L3: 64->16, no relu; sigma = exp(d[:,0]) ----
    {
      bf8 b0 = *(const bf8*)(act + m*ACT_STRIDE + q*8);
      bf8 b1 = *(const bf8*)(act + m*ACT_STRIDE + 32 + q*8);
      f4 c = {0.f,0.f,0.f,0.f};
      c = MFMA16(*(const bf8*)(smem + OFF_W3 + lane*8), b0, c);
      c = MFMA16(*(const bf8*)(smem + OFF_W3 + (64+lane)*8), b1, c);
      us4 pk;
      float d0 = 0.f;
#pragma unroll
      for (int r = 0; r < 4; ++r){
        float v = c[r] + sbias[BO_B3 + q*4 + r];
        if (r == 0) d0 = v;
        pk[r] = f2bfu(v);
      }
      if (q == 0 && gp < nB) out[gp] = expf(d0);   // row 0 = d[:,0]
      *(us4*)(act + m*ACT_STRIDE + q*4) = pk;      // d features 0..15
    }
    wfence();

    // ---- C1: 16->64 relu (K zero-padded to 32) ----
    {
      bf8 bc;
      if (q < 2){
        bc = *(const bf8*)(act + m*ACT_STRIDE + q*8);
      } else {
#pragma unroll
        for (int j = 0; j < 8; ++j) bc[j] = (__bf16)0.f;
      }
      f4 acc[4];
#pragma unroll
      for (int t = 0; t < 4; ++t){
        f4 c = {0.f,0.f,0.f,0.f};
        acc[t] = MFMA16(*(const bf8*)(smem + OFF_CW1 + (t*64+lane)*8), bc, c);
      }
#pragma unroll
      for (int t = 0; t < 4; ++t){
        us4 pk;
#pragma unroll
        for (int r = 0; r < 4; ++r){
          float v = fmaxf(acc[t][r] + sbias[BO_CB1 + t*16 + q*4 + r], 0.f);
          pk[r] = f2bfu(v);
        }
        *(us4*)(act + m*ACT_STRIDE + t*16 + q*4) = pk;
      }
    }
    wfence();

    // ---- C2, C3: 64->64 relu ----
    layer64(smem+OFF_CW2, sbias+BO_CB2, act, lane, true);
    wfence();
    layer64(smem+OFF_CW3, sbias+BO_CB3, act, lane, true);
    wfence();

    // ---- C4: 64->3, sigmoid ----
    {
      bf8 b0 = *(const bf8*)(act + m*ACT_STRIDE + q*8);
      bf8 b1 = *(const bf8*)(act + m*ACT_STRIDE + 32 + q*8);
      f4 c = {0.f,0.f,0.f,0.f};
      c = MFMA16(*(const bf8*)(smem + OFF_CW4 + lane*8), b0, c);
      c = MFMA16(*(const bf8*)(smem + OFF_CW4 + (64+lane)*8), b1, c);
      if (q == 0 && gp < nB){
#pragma unroll
        for (int r = 0; r < 3; ++r){
          float v = c[r] + sbias[BO_CB4 + r];
          out[nB + gp*3 + r] = 1.f/(1.f + expf(-v));
        }
      }
    }
    wfence();   // C4 act read -> next iter L1 write (wave-local)

    g = gn;   // rotate prefetch (dead on it==3)
  }
}

extern "C" void kernel_launch(void* const* d_in, const int* in_sizes, int n_in,
                              void* d_out, int out_size, void* d_ws, size_t ws_size,
                              hipStream_t stream) {
  (void)n_in; (void)out_size; (void)d_ws; (void)ws_size;
  const int nB = in_sizes[0] / 3;
  const int blocks = (nB + 255) / 256;
  nerf_fused<<<dim3(blocks), dim3(256), 0, stream>>>(
      (const float*)d_in[0],  (const float*)d_in[1],
      (const float*)d_in[2],  (const float*)d_in[3],
      (const float*)d_in[4],  (const float*)d_in[5],
      (const float*)d_in[6],  (const float*)d_in[7],
      (const float*)d_in[8],  (const float*)d_in[9],
      (const float*)d_in[10], (const float*)d_in[11],
      (const float*)d_in[12], (const float*)d_in[13],
      (const float*)d_in[14], (const float*)d_in[15],
      (float*)d_out, nB);
}

// Round 5
// 460.810 us; speedup vs baseline: 1.1844x; 1.1844x over previous
//
#include <hip/hip_runtime.h>

typedef __bf16 bf8 __attribute__((ext_vector_type(8)));
typedef float f4 __attribute__((ext_vector_type(4)));
typedef unsigned short us4 __attribute__((ext_vector_type(4)));

#define MFMA16(a,b,c) __builtin_amdgcn_mfma_f32_16x16x32_bf16((a),(b),(c),0,0,0)

#define BLOCK 512
#define NWAVE 8   // waves per block

__device__ __forceinline__ unsigned short f2bfu(float f){
  __bf16 h = (__bf16)f;
  union { __bf16 b; unsigned short u; } v; v.b = h; return v.u;
}

// Wave-local LDS fence: stalls only THIS wave until its DS ops completed.
// Act buffers are wave-private, so this replaces __syncthreads() between
// layers (validated correct in round 4, absmax 0.0).
__device__ __forceinline__ void wfence(){
  asm volatile("s_waitcnt lgkmcnt(0)" ::: "memory");
}

// LDS layout (ushort element offsets)
#define OFF_W1   0       // 32->64 : 1 kstep * 4 mtiles * 512 = 2048
#define OFF_W2   2048    // 64->64 : 2*4*512 = 4096
#define OFF_W3   6144    // 64->16 : 2*1*512 = 1024
#define OFF_CW1  7168    // 16->64 : 1*4*512 = 2048 (zero-padded K)
#define OFF_CW2  9216    // 64->64 : 4096
#define OFF_CW3  13312   // 64->64 : 4096
#define OFF_CW4  17408   // 64->3  : 2*1*512 = 1024 (zero-padded M)
#define OFF_ACT  18432
#define ACT_STRIDE 72    // 64 features + 8 pad
#define SMEM_US  (18432 + NWAVE*16*ACT_STRIDE)   // 55296 B + biases < 64 KB

// bias offsets (floats)
#define BO_B1  0
#define BO_B2  64
#define BO_B3  128
#define BO_CB1 144
#define BO_CB2 208
#define BO_CB3 272
#define BO_CB4 336

// Stage weights from global (fin x fout row-major FP32) into LDS as bf16 in
// A-fragment order: element ((s*MT+t)*64+lane)*8+j holds w[k=s*32+(lane>>4)*8+j][o=t*16+(lane&15)].
template<int FIN,int FOUT,int KS,int MT>
__device__ __forceinline__ void stage_w(const float* w, unsigned short* dst){
  const int total = KS*MT*512;
  for (int e = threadIdx.x; e < total; e += BLOCK){
    int chunk = e >> 9;
    int s = chunk / MT, t = chunk % MT;
    int le = e & 511;
    int lane = le >> 3, j = le & 7;
    int q = lane >> 4, m = lane & 15;
    int i = s*32 + q*8 + j;
    int o = t*16 + m;
    dst[e] = (i < FIN && o < FOUT) ? f2bfu(w[i*FOUT + o]) : (unsigned short)0;
  }
}

// One 64->64 layer for one wave's 16-point tile, LDS act round-trip.
__device__ __forceinline__ void layer64(const unsigned short* wlds, const float* bias,
                                        unsigned short* act, int lane, bool relu){
  const int q = lane >> 4, m = lane & 15;
  bf8 b0 = *(const bf8*)(act + m*ACT_STRIDE + q*8);        // k = 0..31
  bf8 b1 = *(const bf8*)(act + m*ACT_STRIDE + 32 + q*8);   // k = 32..63
  f4 acc[4];
#pragma unroll
  for (int t = 0; t < 4; ++t){
    f4 c = {0.f,0.f,0.f,0.f};
    c = MFMA16(*(const bf8*)(wlds + ((0*4+t)*64+lane)*8), b0, c);
    c = MFMA16(*(const bf8*)(wlds + ((1*4+t)*64+lane)*8), b1, c);
    acc[t] = c;
  }
#pragma unroll
  for (int t = 0; t < 4; ++t){
    us4 pk;
#pragma unroll
    for (int r = 0; r < 4; ++r){
      float v = acc[t][r] + bias[t*16 + q*4 + r];
      if (relu) v = fmaxf(v, 0.f);
      pk[r] = f2bfu(v);
    }
    *(us4*)(act + m*ACT_STRIDE + t*16 + q*4) = pk;
  }
}

__global__ __launch_bounds__(BLOCK) void nerf_fused(
    const float* __restrict__ xin, const float* __restrict__ tab,
    const float* __restrict__ w1,  const float* __restrict__ b1,
    const float* __restrict__ w2,  const float* __restrict__ b2,
    const float* __restrict__ w3,  const float* __restrict__ b3,
    const float* __restrict__ cw1, const float* __restrict__ cb1,
    const float* __restrict__ cw2, const float* __restrict__ cb2,
    const float* __restrict__ cw3, const float* __restrict__ cb3,
    const float* __restrict__ cw4, const float* __restrict__ cb4,
    float* __restrict__ out, int nB)
{
  __shared__ __align__(16) unsigned short smem[SMEM_US];
  __shared__ __align__(16) float sbias[340];
  __shared__ int sres[16];

  stage_w<32,64,1,4>(w1,  smem+OFF_W1);
  stage_w<64,64,2,4>(w2,  smem+OFF_W2);
  stage_w<64,16,2,1>(w3,  smem+OFF_W3);
  stage_w<16,64,1,4>(cw1, smem+OFF_CW1);
  stage_w<64,64,2,4>(cw2, smem+OFF_CW2);
  stage_w<64,64,2,4>(cw3, smem+OFF_CW3);
  stage_w<64, 3,2,1>(cw4, smem+OFF_CW4);
  {
    int t = threadIdx.x;
    if (t < 64){
      sbias[BO_B1 +t] = b1[t];
      sbias[BO_B2 +t] = b2[t];
      sbias[BO_CB1+t] = cb1[t];
      sbias[BO_CB2+t] = cb2[t];
      sbias[BO_CB3+t] = cb3[t];
    }
    if (t < 16) sbias[BO_B3+t] = b3[t];
    if (t < 3)  sbias[BO_CB4+t] = cb4[t];
    if (t < 16){
      const int RES_[16] = {16,20,25,32,40,50,64,80,101,128,161,203,256,322,406,512};
      sres[t] = RES_[t];
    }
  }
  __syncthreads();   // weights/bias staging -> everything (only block barrier)

  const int lane = threadIdx.x & 63, wv = threadIdx.x >> 6;
  const int q = lane >> 4, m = lane & 15;
  unsigned short* act = smem + OFF_ACT + wv*16*ACT_STRIDE;

  int res_[4];
#pragma unroll
  for (int d = 0; d < 4; ++d) res_[d] = sres[4*q + d];

  for (int it = 0; it < 4; ++it){
    const int gp  = blockIdx.x*(BLOCK/NWAVE*8) + wv*64 + it*16 + m;  // block covers 512 points
    const int gpl = min(gp, nB-1);
    const float px = xin[gpl*3+0];
    const float py = xin[gpl*3+1];
    const float pz = xin[gpl*3+2];

    // ---- hash encode: this lane's 8 features ARE its layer-1 B-fragment ----
    bf8 bfrag;
#pragma unroll
    for (int d = 0; d < 4; ++d){
      const int lvl = 4*q + d;
      const int res = res_[d];
      const float sc = 0.5f*(float)(res-1);
      const float xs=(px+1.f)*sc, ys=(py+1.f)*sc, zs=(pz+1.f)*sc;
      const float fx=floorf(xs), fy=floorf(ys), fz=floorf(zs);
      const float wx=xs-fx, wy=ys-fy, wz=zs-fz;
      int ix0=min(max((int)fx,0),res-1);
      int iy0=min(max((int)fy,0),res-1);
      int iz0=min(max((int)fz,0),res-1);
      int ix1=min(ix0+1,res-1), iy1=min(iy0+1,res-1), iz1=min(iz0+1,res-1);
      const bool dense = (lvl < 3);   // 16^3,20^3,25^3 <= 16384
      unsigned X0,X1,Y0,Y1,Z0,Z1;
      if (dense){
        X0=(unsigned)ix0;            X1=(unsigned)ix1;
        Y0=(unsigned)(res*iy0);      Y1=(unsigned)(res*iy1);
        Z0=(unsigned)(res*res*iz0);  Z1=(unsigned)(res*res*iz1);
      } else {
        X0=(unsigned)ix0;                 X1=(unsigned)ix1;
        Y0=(unsigned)iy0*2654435761u;     Y1=(unsigned)iy1*2654435761u;
        Z0=(unsigned)iz0*805459861u;      Z1=(unsigned)iz1*805459861u;
      }
      const float wx0=1.f-wx, wy0=1.f-wy, wz0=1.f-wz;
      float f0=0.f, f1=0.f;
      const float2* tl = (const float2*)tab + (lvl<<14);
#pragma unroll
      for (int c = 0; c < 8; ++c){
        unsigned xc = (c&1)?X1:X0;
        unsigned yc = (c&2)?Y1:Y0;
        unsigned zc = (c&4)?Z1:Z0;
        unsigned idx = dense ? (xc+yc+zc) : ((xc^yc^zc)&16383u);
        float2 tv = tl[idx];
        float wc = ((c&1)?wx:wx0) * ((c&2)?wy:wy0) * ((c&4)?wz:wz0);
        f0 += wc*tv.x;
        f1 += wc*tv.y;
      }
      bfrag[2*d]   = (__bf16)f0;
      bfrag[2*d+1] = (__bf16)f1;
    }

    // ---- L1: 32->64, relu ----
    {
      f4 acc[4];
#pragma unroll
      for (int t = 0; t < 4; ++t){
        f4 c = {0.f,0.f,0.f,0.f};
        acc[t] = MFMA16(*(const bf8*)(smem + OFF_W1 + (t*64+lane)*8), bfrag, c);
      }
#pragma unroll
      for (int t = 0; t < 4; ++t){
        us4 pk;
#pragma unroll
        for (int r = 0; r < 4; ++r){
          float v = fmaxf(acc[t][r] + sbias[BO_B1 + t*16 + q*4 + r], 0.f);
          pk[r] = f2bfu(v);
        }
        *(us4*)(act + m*ACT_STRIDE + t*16 + q*4) = pk;
      }
    }
    wfence();   // L1 act write -> L2 read (wave-local)

    // ---- L2: 64->64 relu ----
    layer64(smem+OFF_W2, sbias+BO_B2, act, lane, true);
    wfence();

    // ---- L3: 64->16, no relu; sigma = exp(d[:,0]) ----
    {
      bf8 b0 = *(const bf8*)(act + m*ACT_STRIDE + q*8);
      bf8 b1 = *(const bf8*)(act + m*ACT_STRIDE + 32 + q*8);
      f4 c = {0.f,0.f,0.f,0.f};
      c = MFMA16(*(const bf8*)(smem + OFF_W3 + lane*8), b0, c);
      c = MFMA16(*(const bf8*)(smem + OFF_W3 + (64+lane)*8), b1, c);
      us4 pk;
      float d0 = 0.f;
#pragma unroll
      for (int r = 0; r < 4; ++r){
        float v = c[r] + sbias[BO_B3 + q*4 + r];
        if (r == 0) d0 = v;
        pk[r] = f2bfu(v);
      }
      if (q == 0 && gp < nB) out[gp] = expf(d0);   // row 0 = d[:,0]
      *(us4*)(act + m*ACT_STRIDE + q*4) = pk;      // d features 0..15
    }
    wfence();

    // ---- C1: 16->64 relu (K zero-padded to 32) ----
    {
      bf8 bc;
      if (q < 2){
        bc = *(const bf8*)(act + m*ACT_STRIDE + q*8);
      } else {
#pragma unroll
        for (int j = 0; j < 8; ++j) bc[j] = (__bf16)0.f;
      }
      f4 acc[4];
#pragma unroll
      for (int t = 0; t < 4; ++t){
        f4 c = {0.f,0.f,0.f,0.f};
        acc[t] = MFMA16(*(const bf8*)(smem + OFF_CW1 + (t*64+lane)*8), bc, c);
      }
#pragma unroll
      for (int t = 0; t < 4; ++t){
        us4 pk;
#pragma unroll
        for (int r = 0; r < 4; ++r){
          float v = fmaxf(acc[t][r] + sbias[BO_CB1 + t*16 + q*4 + r], 0.f);
          pk[r] = f2bfu(v);
        }
        *(us4*)(act + m*ACT_STRIDE + t*16 + q*4) = pk;
      }
    }
    wfence();

    // ---- C2, C3: 64->64 relu ----
    layer64(smem+OFF_CW2, sbias+BO_CB2, act, lane, true);
    wfence();
    layer64(smem+OFF_CW3, sbias+BO_CB3, act, lane, true);
    wfence();

    // ---- C4: 64->3, sigmoid ----
    {
      bf8 b0 = *(const bf8*)(act + m*ACT_STRIDE + q*8);
      bf8 b1 = *(const bf8*)(act + m*ACT_STRIDE + 32 + q*8);
      f4 c = {0.f,0.f,0.f,0.f};
      c = MFMA16(*(const bf8*)(smem + OFF_CW4 + lane*8), b0, c);
      c = MFMA16(*(const bf8*)(smem + OFF_CW4 + (64+lane)*8), b1, c);
      if (q == 0 && gp < nB){
#pragma unroll
        for (int r = 0; r < 3; ++r){
          float v = c[r] + sbias[BO_CB4 + r];
          out[nB + gp*3 + r] = 1.f/(1.f + expf(-v));
        }
      }
    }
    wfence();   // C4 act read -> next iter L1 write (wave-local)
  }
}

extern "C" void kernel_launch(void* const* d_in, const int* in_sizes, int n_in,
                              void* d_out, int out_size, void* d_ws, size_t ws_size,
                              hipStream_t stream) {
  (void)n_in; (void)out_size; (void)d_ws; (void)ws_size;
  const int nB = in_sizes[0] / 3;
  const int pts_per_block = 512;       // 8 waves x 64 points
  const int blocks = (nB + pts_per_block - 1) / pts_per_block;
  nerf_fused<<<dim3(blocks), dim3(BLOCK), 0, stream>>>(
      (const float*)d_in[0],  (const float*)d_in[1],
      (const float*)d_in[2],  (const float*)d_in[3],
      (const float*)d_in[4],  (const float*)d_in[5],
      (const float*)d_in[6],  (const float*)d_in[7],
      (const float*)d_in[8],  (const float*)d_in[9],
      (const float*)d_in[10], (const float*)d_in[11],
      (const float*)d_in[12], (const float*)d_in[13],
      (const float*)d_in[14], (const float*)d_in[15],
      (float*)d_out, nB);
}